// Round 6
// baseline (179.728 us; speedup 1.0000x reference)
//
#include <hip/hip_runtime.h>
#include <math.h>
#include <stdint.h>

typedef unsigned short u16;
typedef __bf16 bf16x8 __attribute__((ext_vector_type(8)));
typedef float f32x4 __attribute__((ext_vector_type(4)));
typedef u16 u16x8 __attribute__((ext_vector_type(8)));

constexpr int Bb = 2, Ss = 2048, Dd = 1024, Hh = 16, Hd = 64, Win = 256;
constexpr int Mtot = Bb * Ss;   // 4096

// ---------- helpers ----------
__device__ __forceinline__ u16 f2bf(float f) {
    uint32_t u = __float_as_uint(f);
    u += 0x7fff + ((u >> 16) & 1);   // RNE
    return (u16)(u >> 16);
}

__device__ __forceinline__ void gload16(const void* g, void* l) {
    __builtin_amdgcn_global_load_lds(
        (const __attribute__((address_space(1))) uint32_t*)g,
        (__attribute__((address_space(3))) uint32_t*)l, 16, 0, 0);
}

// LDS byte address (for inline-asm ds_read): generic -> addrspace(3) -> u32
__device__ __forceinline__ uint32_t laddr(const void* p) {
    return (uint32_t)(uintptr_t)(const __attribute__((address_space(3))) char*)p;
}

// ---------- fp32 -> bf16 convert (vectorized) ----------
__global__ void cvt4(const float* __restrict__ s, u16* __restrict__ d, int n4) {
    int i = blockIdx.x * blockDim.x + threadIdx.x;
    if (i >= n4) return;
    float4 v = reinterpret_cast<const float4*>(s)[i];
    ushort4 o;
    o.x = f2bf(v.x); o.y = f2bf(v.y); o.z = f2bf(v.z); o.w = f2bf(v.w);
    reinterpret_cast<ushort4*>(d)[i] = o;
}

// 4 weight matrices in one dispatch (blockIdx.y selects)
__global__ void cvt4w(const float* __restrict__ s0, const float* __restrict__ s1,
                      const float* __restrict__ s2, const float* __restrict__ s3,
                      u16* __restrict__ d0, u16* __restrict__ d1,
                      u16* __restrict__ d2, u16* __restrict__ d3, int n4) {
    const int wsel = blockIdx.y;
    const float* s = (wsel == 0) ? s0 : (wsel == 1) ? s1 : (wsel == 2) ? s2 : s3;
    u16* d = (wsel == 0) ? d0 : (wsel == 1) ? d1 : (wsel == 2) ? d2 : d3;
    int i = blockIdx.x * blockDim.x + threadIdx.x;
    if (i >= n4) return;
    float4 v = reinterpret_cast<const float4*>(s)[i];
    ushort4 o;
    o.x = f2bf(v.x); o.y = f2bf(v.y); o.z = f2bf(v.z); o.w = f2bf(v.w);
    reinterpret_cast<ushort4*>(d)[i] = o;
}

// ---------- RoPE tables: cos/sin[s][d], freq index = d mod 32 ----------
__global__ void rope_tables(float* __restrict__ ct, float* __restrict__ st) {
    int i = blockIdx.x * blockDim.x + threadIdx.x;   // over Ss*64
    if (i >= Ss * 64) return;
    int s = i >> 6, d = i & 63;
    float invf = powf(10000.0f, -(float)(d & 31) / 32.0f);
    float ang = (float)s * invf;
    ct[i] = cosf(ang);
    st[i] = sinf(ang);
}

// ================== 256x256 8-phase QKV GEMM — asm ds_read ==================
// Same schedule as round 5 (static LDS objects, counted vmcnt(4)/tile), but the
// fragment loads are inline-asm ds_read_b128: SIInsertWaitcnts cannot see them
// as DS ops, so it cannot insert a conservative vmcnt(0) against outstanding
// global_load_lds DMAs (the r4/r5 per-phase drain). Correctness is carried by
// the schedule itself: a buffer is only read >=1 barrier after its loads were
// retired by the per-tile vmcnt(4). Rule-18 fence (sched_barrier(0) after
// lgkmcnt(0)) stops MFMA hoisting past the wait.

#define PH_PRE                                                 \
    __builtin_amdgcn_s_barrier();                              \
    asm volatile("s_waitcnt lgkmcnt(0)" ::: "memory");         \
    __builtin_amdgcn_sched_barrier(0);                         \
    __builtin_amdgcn_s_setprio(1);

#define VM4 asm volatile("s_waitcnt vmcnt(4)" ::: "memory");
#define VM0 asm volatile("s_waitcnt vmcnt(0)" ::: "memory");
#define VMNONE

#define STAGE_A(DST, H, KT)                                                   \
    { _Pragma("unroll") for (int p_ = 0; p_ < 2; ++p_) {                      \
        int x_ = (p_ * 512 + t) * 16;                                         \
        int r_ = x_ >> 7, g_ = ((x_ >> 4) & 7) ^ (r_ & 7);                    \
        gload16(A + (size_t)(m0 + (H) * 128 + r_) * 1024 + (KT) * 64 + g_ * 8,\
                (char*)(DST) + x_); } }

#define STAGE_B(DST, H, KT)                                                   \
    { _Pragma("unroll") for (int p_ = 0; p_ < 2; ++p_) {                      \
        int x_ = (p_ * 512 + t) * 16;                                         \
        int r_ = x_ >> 7, g_ = ((x_ >> 4) & 7) ^ (r_ & 7);                    \
        gload16(Wm + (size_t)(n0g + (H) * 128 + r_) * 1024 + (KT) * 64 + g_ * 8,\
                (char*)(DST) + x_); } }

#define RD_A(SRC, DST)                                                        \
    _Pragma("unroll") for (int fm_ = 0; fm_ < 4; ++fm_)                       \
    _Pragma("unroll") for (int ks_ = 0; ks_ < 2; ++ks_) {                     \
        int r_ = wm * 64 + fm_ * 16 + lr;                                     \
        int g_ = (ks_ * 4 + hi) ^ (r_ & 7);                                   \
        uint32_t a_ = laddr(SRC) + (uint32_t)(r_ * 128 + g_ * 16);            \
        asm volatile("ds_read_b128 %0, %1" : "=v"(DST[fm_][ks_]) : "v"(a_));  \
    }

#define RD_B(SRC, DST)                                                        \
    _Pragma("unroll") for (int fn_ = 0; fn_ < 2; ++fn_)                       \
    _Pragma("unroll") for (int ks_ = 0; ks_ < 2; ++ks_) {                     \
        int r_ = wn * 32 + fn_ * 16 + lr;                                     \
        int g_ = (ks_ * 4 + hi) ^ (r_ & 7);                                   \
        uint32_t a_ = laddr(SRC) + (uint32_t)(r_ * 128 + g_ * 16);            \
        asm volatile("ds_read_b128 %0, %1" : "=v"(DST[fn_][ks_]) : "v"(a_));  \
    }

#define QUAD(AH, BH, AFR, BFR)                                                \
    _Pragma("unroll") for (int fm_ = 0; fm_ < 4; ++fm_)                       \
    _Pragma("unroll") for (int fn_ = 0; fn_ < 2; ++fn_) {                     \
        acc[AH][BH][fm_][fn_] = __builtin_amdgcn_mfma_f32_16x16x32_bf16(      \
            AFR[fm_][0], BFR[fn_][0], acc[AH][BH][fm_][fn_], 0, 0, 0);        \
        acc[AH][BH][fm_][fn_] = __builtin_amdgcn_mfma_f32_16x16x32_bf16(      \
            AFR[fm_][1], BFR[fn_][1], acc[AH][BH][fm_][fn_], 0, 0, 0);        \
    }

#define TILE(SA0, SA1, SB0, SB1, NA1, NB1, KT, STG1, STG2, VMF)               \
    RD_A(SA0, aF0) RD_B(SB0, bF0)                                             \
    if (STG1) { STAGE_A(NA1, 1, (KT) + 1) }                                   \
    PH_PRE QUAD(0, 0, aF0, bF0)                                               \
    __builtin_amdgcn_s_setprio(0); __builtin_amdgcn_s_barrier();              \
    RD_A(SA1, aF1)                                                            \
    if (STG1) { STAGE_B(NB1, 1, (KT) + 1) }                                   \
    PH_PRE QUAD(1, 0, aF1, bF0)                                               \
    __builtin_amdgcn_s_setprio(0); __builtin_amdgcn_s_barrier();              \
    RD_B(SB1, bF1)                                                            \
    if (STG2) { STAGE_B(SB0, 0, (KT) + 2) }                                   \
    PH_PRE QUAD(0, 1, aF0, bF1)                                               \
    __builtin_amdgcn_s_setprio(0); __builtin_amdgcn_s_barrier();              \
    if (STG2) { STAGE_A(SA0, 0, (KT) + 2) }                                   \
    PH_PRE QUAD(1, 1, aF1, bF1)                                               \
    __builtin_amdgcn_s_setprio(0); VMF __builtin_amdgcn_s_barrier();

__global__ __launch_bounds__(512, 2) void gemm_qkv(
    const u16* __restrict__ A,
    const u16* __restrict__ W0, const u16* __restrict__ W1, const u16* __restrict__ W2,
    u16* __restrict__ Qo, u16* __restrict__ Ko, u16* __restrict__ Vo,
    const float* __restrict__ ct, const float* __restrict__ st)
{
    // 8 distinct LDS objects: [buf][half] for A and B, 16 KiB each = 128 KiB
    __shared__ u16 sA00[8192], sA01[8192], sA10[8192], sA11[8192];
    __shared__ u16 sB00[8192], sB01[8192], sB10[8192], sB11[8192];

    const int t = threadIdx.x;
    const int l = t & 63, w = t >> 6;
    const int wm = w >> 2, wn = w & 3;            // 2M x 4N wave grid
    const int lr = l & 15, hi = l >> 4;

    int wg = blockIdx.x;
    wg = (wg & 7) * 24 + (wg >> 3);               // XCD swizzle (192 = 8*24, bijective)
    const int bx = wg & 15, by = wg >> 4;         // 16 M-tiles x 12 N-tiles
    const int m0 = bx * 256;
    const int mat = by >> 2;                      // 0:Q 1:K 2:V
    const int n0g = (by & 3) * 256;               // col base within its 1024 matrix
    const u16* Wm = (mat == 0) ? W0 : (mat == 1) ? W1 : W2;
    u16* Cm = (mat == 0) ? Qo : (mat == 1) ? Ko : Vo;

    f32x4 acc[2][2][4][2] = {};
    bf16x8 aF0[4][2], aF1[4][2], bF0[2][2], bF1[2][2];

    // prologue: tile0 all 4 halves + tile1 B0,A0; then retire tile0 (vmcnt 4)
    STAGE_B(sB00, 0, 0) STAGE_A(sA00, 0, 0) STAGE_A(sA01, 1, 0) STAGE_B(sB01, 1, 0)
    STAGE_B(sB10, 0, 1) STAGE_A(sA10, 0, 1)
    VM4
    __builtin_amdgcn_s_barrier();

    for (int it = 0; it < 7; ++it) {
        const int kt = 2 * it;
        TILE(sA00, sA01, sB00, sB01, sA11, sB11, kt,     true, true, VM4)
        TILE(sA10, sA11, sB10, sB11, sA01, sB01, kt + 1, true, true, VM4)
    }
    // tail: tiles 14,15 (no stages past K, drain at 14)
    TILE(sA00, sA01, sB00, sB01, sA11, sB11, 14, true,  false, VM0)
    TILE(sA10, sA11, sB10, sB11, sA01, sB01, 15, false, false, VMNONE)

    // ---- epilogue: RoPE (Q,K) + bf16 cast, write [bh][s][64] ----
    const bool dorope = (mat < 2);
#pragma unroll
    for (int ah = 0; ah < 2; ++ah) {
#pragma unroll
        for (int bh = 0; bh < 2; ++bh) {
#pragma unroll
            for (int fm = 0; fm < 4; ++fm) {
#pragma unroll
                for (int fn = 0; fn < 2; ++fn) {
#pragma unroll
                    for (int j = 0; j < 4; ++j) {
                        int row = m0 + ah * 128 + wm * 64 + fm * 16 + hi * 4 + j;
                        int cim = n0g + bh * 128 + wn * 32 + fn * 16 + lr;
                        float v = acc[ah][bh][fm][fn][j];
                        float vp = __shfl_xor(v, 1);   // col^1 lives in lane^1
                        int b = row >> 11, sIdx = row & 2047;
                        int h = cim >> 6, d = cim & 63;
                        float outv = v;
                        if (dorope) {
                            float c = ct[sIdx * 64 + d], sn = st[sIdx * 64 + d];
                            outv = (d & 1) ? (v * c + vp * sn) : (v * c - vp * sn);
                        }
                        Cm[(((size_t)(b * 16 + h)) * 2048 + sIdx) * 64 + d] = f2bf(outv);
                    }
                }
            }
        }
    }
}

// ---------- bf16 MFMA GEMM (m97-style), used for the Wo projection ----------
__global__ __launch_bounds__(256) void gemm_wo(
    const u16* __restrict__ A, const u16* __restrict__ Bw,
    float* __restrict__ C, int M, int N, int Kd)
{
    __shared__ u16 sA[128 * 32];
    __shared__ u16 sB[128 * 32];

    const int t = threadIdx.x, l = t & 63, w = t >> 6;
    const int wm = w >> 1, wn = w & 1;
    const int m0 = blockIdx.x * 128, n0 = blockIdx.y * 128;
    const int lr = l & 15, kg = l >> 4;

    f32x4 acc[4][4] = {};

    for (int k0 = 0; k0 < Kd; k0 += 32) {
        __syncthreads();
#pragma unroll
        for (int p = 0; p < 2; ++p) {
            int i = p * 256 + t;
            int r = i >> 2, c = (i & 3) * 8;
            gload16(A  + (size_t)(m0 + r) * Kd + k0 + c, &sA[i * 8]);
            gload16(Bw + (size_t)(n0 + r) * Kd + k0 + c, &sB[i * 8]);
        }
        __syncthreads();

        bf16x8 af[4], bfr[4];
#pragma unroll
        for (int im = 0; im < 4; ++im)
            af[im] = *reinterpret_cast<const bf16x8*>(&sA[(wm * 64 + im * 16 + lr) * 32 + kg * 8]);
#pragma unroll
        for (int in = 0; in < 4; ++in)
            bfr[in] = *reinterpret_cast<const bf16x8*>(&sB[(wn * 64 + in * 16 + lr) * 32 + kg * 8]);
#pragma unroll
        for (int im = 0; im < 4; ++im)
#pragma unroll
            for (int in = 0; in < 4; ++in)
                acc[im][in] = __builtin_amdgcn_mfma_f32_16x16x32_bf16(af[im], bfr[in], acc[im][in], 0, 0, 0);
    }

#pragma unroll
    for (int im = 0; im < 4; ++im)
#pragma unroll
        for (int in = 0; in < 4; ++in)
#pragma unroll
            for (int j = 0; j < 4; ++j) {
                int row = m0 + wm * 64 + im * 16 + kg * 4 + j;
                int col = n0 + wn * 64 + in * 16 + lr;
                C[(size_t)row * N + col] = acc[im][in][j];
            }
}

// ---------- MFMA flash attention, window=256 ----------
__global__ __launch_bounds__(256) void fattn(
    const u16* __restrict__ Qb, const u16* __restrict__ Kb,
    const u16* __restrict__ Vb, u16* __restrict__ O)
{
    __shared__ u16 sQ[64 * 64];
    __shared__ u16 sK[64 * 64];
    __shared__ u16 sVT[64 * 64];
    __shared__ u16 sP[4][16 * 64];

    const int t = threadIdx.x, l = t & 63, w = t >> 6;
    const int lo = l & 15, hi = l >> 4;
    const int qt = blockIdx.x, bh = blockIdx.y;
    const int q0 = qt * 64;

    const char* Qg = (const char*)(Qb + ((size_t)bh * Ss + q0) * 64);
#pragma unroll
    for (int p = 0; p < 2; ++p) {
        uint32_t x = (uint32_t)(w * 2 + p) * 1024 + l * 16;
        uint32_t sx = x ^ (((x >> 7) & 7) << 4);
        gload16(Qg + sx, (char*)sQ + x);
    }
    __syncthreads();

    bf16x8 qf[2];
#pragma unroll
    for (int ck = 0; ck < 2; ++ck) {
        uint32_t b = (uint32_t)(w * 16 + lo) * 128 + ck * 64 + hi * 16;
        b ^= ((lo & 7) << 4);
        qf[ck] = *reinterpret_cast<const bf16x8*>((const char*)sQ + b);
    }

    f32x4 o[4] = {};
    float mj[4], lj[4];
#pragma unroll
    for (int j = 0; j < 4; ++j) { mj[j] = -1e30f; lj[j] = 0.f; }

    const int jt0 = (qt >= 4) ? qt - 4 : 0;
    for (int jt = jt0; jt <= qt; ++jt) {
        __syncthreads();
        const char* Kg = (const char*)(Kb + ((size_t)bh * Ss + jt * 64) * 64);
#pragma unroll
        for (int p = 0; p < 2; ++p) {
            uint32_t x = (uint32_t)(w * 2 + p) * 1024 + l * 16;
            uint32_t sx = x ^ (((x >> 7) & 7) << 4);
            gload16(Kg + sx, (char*)sK + x);
        }
        const u16* Vg = Vb + ((size_t)bh * Ss + jt * 64) * 64;
#pragma unroll
        for (int p = 0; p < 2; ++p) {
            int c = p * 256 + t;
            int kr = c >> 3, dc = (c & 7) * 8;
            u16x8 vv = *reinterpret_cast<const u16x8*>(Vg + (size_t)kr * 64 + dc);
#pragma unroll
            for (int ii = 0; ii < 8; ++ii) {
                int d = dc + ii;
                uint32_t b = ((uint32_t)d * 128 + kr * 2) ^ (((uint32_t)(d & 7)) << 4);
                *(u16*)((char*)sVT + b) = vv[ii];
            }
        }
        __syncthreads();

        f32x4 s4[4] = {};
#pragma unroll
        for (int ck = 0; ck < 2; ++ck) {
#pragma unroll
            for (int nb = 0; nb < 4; ++nb) {
                uint32_t b = (uint32_t)(nb * 16 + lo) * 128 + ck * 64 + hi * 16;
                b ^= ((lo & 7) << 4);
                bf16x8 kf = *reinterpret_cast<const bf16x8*>((const char*)sK + b);
                s4[nb] = __builtin_amdgcn_mfma_f32_16x16x32_bf16(qf[ck], kf, s4[nb], 0, 0, 0);
            }
        }

        const int qbase = q0 + w * 16 + hi * 4;
#pragma unroll
        for (int nb = 0; nb < 4; ++nb) {
            int k = jt * 64 + nb * 16 + lo;
#pragma unroll
            for (int j = 0; j < 4; ++j) {
                int q = qbase + j;
                float v = s4[nb][j] * 0.125f;
                bool ok = (k <= q) && (q - k < Win);
                s4[nb][j] = ok ? v : -1e30f;
            }
        }

#pragma unroll
        for (int j = 0; j < 4; ++j) {
            float tm = fmaxf(fmaxf(s4[0][j], s4[1][j]), fmaxf(s4[2][j], s4[3][j]));
            tm = fmaxf(tm, __shfl_xor(tm, 1));
            tm = fmaxf(tm, __shfl_xor(tm, 2));
            tm = fmaxf(tm, __shfl_xor(tm, 4));
            tm = fmaxf(tm, __shfl_xor(tm, 8));
            float nm = fmaxf(fmaxf(mj[j], tm), -1e20f);
            float sc = __expf(mj[j] - nm);
            mj[j] = nm;
            lj[j] *= sc;
#pragma unroll
            for (int nb = 0; nb < 4; ++nb) o[nb][j] *= sc;
            float ps = 0.f;
#pragma unroll
            for (int nb = 0; nb < 4; ++nb) {
                float p = __expf(s4[nb][j] - nm);
                ps += p;
                s4[nb][j] = p;
            }
            lj[j] += ps;
        }

#pragma unroll
        for (int nb = 0; nb < 4; ++nb) {
#pragma unroll
            for (int j = 0; j < 4; ++j) {
                int r = hi * 4 + j;
                uint32_t b = ((uint32_t)r * 128 + (nb * 16 + lo) * 2) ^ (((uint32_t)(r & 7)) << 4);
                *(u16*)((char*)&sP[w][0] + b) = f2bf(s4[nb][j]);
            }
        }

#pragma unroll
        for (int ck = 0; ck < 2; ++ck) {
            uint32_t bp = ((uint32_t)lo * 128 + ck * 64 + hi * 16) ^ (((uint32_t)(lo & 7)) << 4);
            bf16x8 pa = *reinterpret_cast<const bf16x8*>((const char*)&sP[w][0] + bp);
#pragma unroll
            for (int nb = 0; nb < 4; ++nb) {
                uint32_t bb = ((uint32_t)(nb * 16 + lo) * 128 + ck * 64 + hi * 16) ^ (((uint32_t)(lo & 7)) << 4);
                bf16x8 vf = *reinterpret_cast<const bf16x8*>((const char*)sVT + bb);
                o[nb] = __builtin_amdgcn_mfma_f32_16x16x32_bf16(pa, vf, o[nb], 0, 0, 0);
            }
        }
    }

#pragma unroll
    for (int j = 0; j < 4; ++j) {
        float s = lj[j];
        s += __shfl_xor(s, 1);
        s += __shfl_xor(s, 2);
        s += __shfl_xor(s, 4);
        s += __shfl_xor(s, 8);
        lj[j] = 1.0f / s;
    }
    const int bq = bh >> 4, h = bh & 15;
#pragma unroll
    for (int nb = 0; nb < 4; ++nb) {
#pragma unroll
        for (int j = 0; j < 4; ++j) {
            int q = q0 + w * 16 + hi * 4 + j;
            int d = nb * 16 + lo;
            O[((size_t)(bq * Ss + q)) * Dd + h * 64 + d] = f2bf(o[nb][j] * lj[j]);
        }
    }
}

// ---------- launch ----------
extern "C" void kernel_launch(void* const* d_in, const int* in_sizes, int n_in,
                              void* d_out, int out_size, void* d_ws, size_t ws_size,
                              hipStream_t stream) {
    const float* x  = (const float*)d_in[0];
    const float* Wq = (const float*)d_in[1];
    const float* Wk = (const float*)d_in[2];
    const float* Wv = (const float*)d_in[3];
    const float* Wo = (const float*)d_in[4];
    float* out = (float*)d_out;

    char* ws = (char*)d_ws;
    size_t off = 0;
    auto carve = [&](size_t bytes) -> char* {
        char* p = ws + off;
        off += (bytes + 255) & ~(size_t)255;
        return p;
    };
    float* cosT = (float*)carve((size_t)Ss * 64 * 4);
    float* sinT = (float*)carve((size_t)Ss * 64 * 4);
    u16* xb  = (u16*)carve((size_t)Mtot * Dd * 2);
    u16* wqb = (u16*)carve((size_t)Dd * Dd * 2);
    u16* wkb = (u16*)carve((size_t)Dd * Dd * 2);
    u16* wvb = (u16*)carve((size_t)Dd * Dd * 2);
    u16* wob = (u16*)carve((size_t)Dd * Dd * 2);
    u16* Qbb = (u16*)carve((size_t)Mtot * Dd * 2);
    u16* Kbb = (u16*)carve((size_t)Mtot * Dd * 2);
    u16* Vbb = (u16*)carve((size_t)Mtot * Dd * 2);
    u16* attb = (u16*)carve((size_t)Mtot * Dd * 2);

    const int nx4 = Mtot * Dd / 4, nw4 = Dd * Dd / 4;
    cvt4<<<nx4 / 256, 256, 0, stream>>>(x, xb, nx4);
    cvt4w<<<dim3(nw4 / 256, 4), 256, 0, stream>>>(Wq, Wk, Wv, Wo, wqb, wkb, wvb, wob, nw4);
    rope_tables<<<(Ss * 64) / 256, 256, 0, stream>>>(cosT, sinT);

    gemm_qkv<<<dim3(192), 512, 0, stream>>>(xb, wqb, wkb, wvb, Qbb, Kbb, Vbb, cosT, sinT);

    fattn<<<dim3(Ss / 64, Bb * Hh), 256, 0, stream>>>(Qbb, Kbb, Vbb, attb);

    gemm_wo<<<dim3(Mtot / 128, Dd / 128), 256, 0, stream>>>(
        attb, wob, out, Mtot, Dd, Dd);
}

// Round 7
// 121.540 us; speedup vs baseline: 1.4787x; 1.4787x over previous
//
#include <hip/hip_runtime.h>
#include <math.h>
#include <stdint.h>

typedef unsigned short u16;
typedef __bf16 bf16x8 __attribute__((ext_vector_type(8)));
typedef float f32x4 __attribute__((ext_vector_type(4)));
typedef u16 u16x8 __attribute__((ext_vector_type(8)));

constexpr int Bb = 2, Ss = 2048, Dd = 1024, Hh = 16, Hd = 64, Win = 256;
constexpr int Mtot = Bb * Ss;   // 4096

// ---------- helpers ----------
__device__ __forceinline__ u16 f2bf(float f) {
    uint32_t u = __float_as_uint(f);
    u += 0x7fff + ((u >> 16) & 1);   // RNE
    return (u16)(u >> 16);
}

__device__ __forceinline__ void gload16(const void* g, void* l) {
    __builtin_amdgcn_global_load_lds(
        (const __attribute__((address_space(1))) uint32_t*)g,
        (__attribute__((address_space(3))) uint32_t*)l, 16, 0, 0);
}

// ---------- merged prep: x->bf16, 4 weights->bf16, rope tables (1 launch) ----------
// 1-D grid: [0,4096) x | [4096,8192) weights (1024 blocks each) | [8192,8704) tables
__global__ void prep(const float* __restrict__ x,
                     const float* __restrict__ Wq, const float* __restrict__ Wk,
                     const float* __restrict__ Wv, const float* __restrict__ Wo,
                     u16* __restrict__ xb,
                     u16* __restrict__ wqb, u16* __restrict__ wkb,
                     u16* __restrict__ wvb, u16* __restrict__ wob,
                     float* __restrict__ ct, float* __restrict__ st) {
    const int bid = blockIdx.x;
    if (bid < 8192) {
        const float* s;
        u16* d;
        int i;
        if (bid < 4096) {
            s = x; d = xb; i = bid * 256 + threadIdx.x;
        } else {
            int wsel = (bid - 4096) >> 10;
            i = ((bid - 4096) & 1023) * 256 + threadIdx.x;
            s = (wsel == 0) ? Wq : (wsel == 1) ? Wk : (wsel == 2) ? Wv : Wo;
            d = (wsel == 0) ? wqb : (wsel == 1) ? wkb : (wsel == 2) ? wvb : wob;
        }
        float4 v = reinterpret_cast<const float4*>(s)[i];
        ushort4 o;
        o.x = f2bf(v.x); o.y = f2bf(v.y); o.z = f2bf(v.z); o.w = f2bf(v.w);
        reinterpret_cast<ushort4*>(d)[i] = o;
    } else {
        int i = (bid - 8192) * 256 + threadIdx.x;    // over Ss*64
        int s = i >> 6, d = i & 63;
        float invf = powf(10000.0f, -(float)(d & 31) / 32.0f);
        float ang = (float)s * invf;
        ct[i] = cosf(ang);
        st[i] = sinf(ang);
    }
}

// ---------- 2-phase double-buffered 128x128 bf16 MFMA GEMM ----------
// C[m][n] = sum_k A[m][k] * Bw[n][k].  BK=32, 4 waves (2x2), 16 MFMA/wave/tile.
// Pipeline (T3 minimum recipe): issue next tile's global_load_lds BEFORE the
// current tile's ds_read+MFMA; single __syncthreads() per tile after MFMA
// (its implicit vmcnt(0) drain lands AFTER the compute -> latency hidden).
// Static named buffers, fully unrolled 2-tile loop: no runtime LDS indexing.
// Stage-source XOR swizzle g^=(r&3): LDS slot (r,c) holds global granule
// c^(r&3); frag read at slot kg^(row&3) -> 64B-stride conflict 8way->4way.
// MODE 0: fused RoPE (z<2) + bf16 cast, write [bh][s][64].  MODE 1: fp32 [M][N].
template <int MODE>
__global__ __launch_bounds__(256) void gemm_k(
    const u16* __restrict__ A,
    const u16* __restrict__ B0, const u16* __restrict__ B1, const u16* __restrict__ B2,
    void* __restrict__ C0, void* __restrict__ C1, void* __restrict__ C2,
    const float* __restrict__ ct, const float* __restrict__ st,
    int M, int N, int Kd)
{
    const u16* Bw = (blockIdx.z == 0) ? B0 : (blockIdx.z == 1) ? B1 : B2;
    void* C = (blockIdx.z == 0) ? C0 : (blockIdx.z == 1) ? C1 : C2;

    __shared__ u16 sA0[128 * 32], sA1[128 * 32];
    __shared__ u16 sB0[128 * 32], sB1[128 * 32];

    const int t = threadIdx.x, l = t & 63, w = t >> 6;
    const int wm = w >> 1, wn = w & 1;
    const int m0 = blockIdx.x * 128, n0 = blockIdx.y * 128;
    const int lr = l & 15, kg = l >> 4;

    f32x4 acc[4][4] = {};

#define STAGE(SA, SB, KT)                                                     \
    { _Pragma("unroll") for (int p_ = 0; p_ < 2; ++p_) {                      \
        int i_ = p_ * 256 + t;                                                \
        int r_ = i_ >> 2, g_ = (i_ & 3) ^ (r_ & 3);                           \
        gload16(A  + (size_t)(m0 + r_) * Kd + (KT) * 32 + g_ * 8, &SA[i_ * 8]);\
        gload16(Bw + (size_t)(n0 + r_) * Kd + (KT) * 32 + g_ * 8, &SB[i_ * 8]);\
    } }

#define COMPUTE(SA, SB)                                                       \
    { bf16x8 af_[4], bf_[4];                                                  \
      _Pragma("unroll") for (int im_ = 0; im_ < 4; ++im_) {                   \
          int r_ = wm * 64 + im_ * 16 + lr;                                   \
          int g_ = kg ^ (r_ & 3);                                             \
          af_[im_] = *reinterpret_cast<const bf16x8*>(&SA[r_ * 32 + g_ * 8]); \
      }                                                                       \
      _Pragma("unroll") for (int in_ = 0; in_ < 4; ++in_) {                   \
          int r_ = wn * 64 + in_ * 16 + lr;                                   \
          int g_ = kg ^ (r_ & 3);                                             \
          bf_[in_] = *reinterpret_cast<const bf16x8*>(&SB[r_ * 32 + g_ * 8]); \
      }                                                                       \
      _Pragma("unroll") for (int im_ = 0; im_ < 4; ++im_)                     \
      _Pragma("unroll") for (int in_ = 0; in_ < 4; ++in_)                     \
          acc[im_][in_] = __builtin_amdgcn_mfma_f32_16x16x32_bf16(            \
              af_[im_], bf_[in_], acc[im_][in_], 0, 0, 0);                    \
    }

    const int NT = Kd / 32;   // 32 for Kd=1024 (even)
    STAGE(sA0, sB0, 0)
    __syncthreads();
    for (int kt = 0; kt < NT; kt += 2) {
        if (kt + 1 < NT) STAGE(sA1, sB1, kt + 1)
        COMPUTE(sA0, sB0)
        __syncthreads();
        if (kt + 2 < NT) STAGE(sA0, sB0, kt + 2)
        COMPUTE(sA1, sB1)
        __syncthreads();
    }
#undef STAGE
#undef COMPUTE

    const bool dorope = (MODE == 0) && (blockIdx.z < 2);
#pragma unroll
    for (int im = 0; im < 4; ++im) {
#pragma unroll
        for (int in = 0; in < 4; ++in) {
#pragma unroll
            for (int j = 0; j < 4; ++j) {
                int row = m0 + wm * 64 + im * 16 + kg * 4 + j;
                int col = n0 + wn * 64 + in * 16 + lr;
                float v = acc[im][in][j];
                if (MODE == 0) {
                    // partner for rotate-half: col^1 lives in lane l^1, same regs
                    float vp = __shfl_xor(v, 1);
                    int b = row >> 11, s = row & 2047;
                    int h = col >> 6, d = col & 63;
                    float outv = v;
                    if (dorope) {
                        float c = ct[s * 64 + d], sn = st[s * 64 + d];
                        outv = (col & 1) ? (v * c + vp * sn) : (v * c - vp * sn);
                    }
                    ((u16*)C)[(((size_t)(b * 16 + h)) * 2048 + s) * 64 + d] = f2bf(outv);
                } else {
                    ((float*)C)[(size_t)row * N + col] = v;
                }
            }
        }
    }
}

// ---------- MFMA flash attention, window=256 (unchanged from r3) ----------
__global__ __launch_bounds__(256) void fattn(
    const u16* __restrict__ Qb, const u16* __restrict__ Kb,
    const u16* __restrict__ Vb, u16* __restrict__ O)
{
    __shared__ u16 sQ[64 * 64];
    __shared__ u16 sK[64 * 64];
    __shared__ u16 sVT[64 * 64];
    __shared__ u16 sP[4][16 * 64];

    const int t = threadIdx.x, l = t & 63, w = t >> 6;
    const int lo = l & 15, hi = l >> 4;
    const int qt = blockIdx.x, bh = blockIdx.y;
    const int q0 = qt * 64;

    const char* Qg = (const char*)(Qb + ((size_t)bh * Ss + q0) * 64);
#pragma unroll
    for (int p = 0; p < 2; ++p) {
        uint32_t x = (uint32_t)(w * 2 + p) * 1024 + l * 16;
        uint32_t sx = x ^ (((x >> 7) & 7) << 4);
        gload16(Qg + sx, (char*)sQ + x);
    }
    __syncthreads();

    bf16x8 qf[2];
#pragma unroll
    for (int ck = 0; ck < 2; ++ck) {
        uint32_t b = (uint32_t)(w * 16 + lo) * 128 + ck * 64 + hi * 16;
        b ^= ((lo & 7) << 4);
        qf[ck] = *reinterpret_cast<const bf16x8*>((const char*)sQ + b);
    }

    f32x4 o[4] = {};
    float mj[4], lj[4];
#pragma unroll
    for (int j = 0; j < 4; ++j) { mj[j] = -1e30f; lj[j] = 0.f; }

    const int jt0 = (qt >= 4) ? qt - 4 : 0;
    for (int jt = jt0; jt <= qt; ++jt) {
        __syncthreads();
        const char* Kg = (const char*)(Kb + ((size_t)bh * Ss + jt * 64) * 64);
#pragma unroll
        for (int p = 0; p < 2; ++p) {
            uint32_t x = (uint32_t)(w * 2 + p) * 1024 + l * 16;
            uint32_t sx = x ^ (((x >> 7) & 7) << 4);
            gload16(Kg + sx, (char*)sK + x);
        }
        const u16* Vg = Vb + ((size_t)bh * Ss + jt * 64) * 64;
#pragma unroll
        for (int p = 0; p < 2; ++p) {
            int c = p * 256 + t;
            int kr = c >> 3, dc = (c & 7) * 8;
            u16x8 vv = *reinterpret_cast<const u16x8*>(Vg + (size_t)kr * 64 + dc);
#pragma unroll
            for (int ii = 0; ii < 8; ++ii) {
                int d = dc + ii;
                uint32_t b = ((uint32_t)d * 128 + kr * 2) ^ (((uint32_t)(d & 7)) << 4);
                *(u16*)((char*)sVT + b) = vv[ii];
            }
        }
        __syncthreads();

        f32x4 s4[4] = {};
#pragma unroll
        for (int ck = 0; ck < 2; ++ck) {
#pragma unroll
            for (int nb = 0; nb < 4; ++nb) {
                uint32_t b = (uint32_t)(nb * 16 + lo) * 128 + ck * 64 + hi * 16;
                b ^= ((lo & 7) << 4);
                bf16x8 kf = *reinterpret_cast<const bf16x8*>((const char*)sK + b);
                s4[nb] = __builtin_amdgcn_mfma_f32_16x16x32_bf16(qf[ck], kf, s4[nb], 0, 0, 0);
            }
        }

        const int qbase = q0 + w * 16 + hi * 4;
#pragma unroll
        for (int nb = 0; nb < 4; ++nb) {
            int k = jt * 64 + nb * 16 + lo;
#pragma unroll
            for (int j = 0; j < 4; ++j) {
                int q = qbase + j;
                float v = s4[nb][j] * 0.125f;
                bool ok = (k <= q) && (q - k < Win);
                s4[nb][j] = ok ? v : -1e30f;
            }
        }

#pragma unroll
        for (int j = 0; j < 4; ++j) {
            float tm = fmaxf(fmaxf(s4[0][j], s4[1][j]), fmaxf(s4[2][j], s4[3][j]));
            tm = fmaxf(tm, __shfl_xor(tm, 1));
            tm = fmaxf(tm, __shfl_xor(tm, 2));
            tm = fmaxf(tm, __shfl_xor(tm, 4));
            tm = fmaxf(tm, __shfl_xor(tm, 8));
            float nm = fmaxf(fmaxf(mj[j], tm), -1e20f);
            float sc = __expf(mj[j] - nm);
            mj[j] = nm;
            lj[j] *= sc;
#pragma unroll
            for (int nb = 0; nb < 4; ++nb) o[nb][j] *= sc;
            float ps = 0.f;
#pragma unroll
            for (int nb = 0; nb < 4; ++nb) {
                float p = __expf(s4[nb][j] - nm);
                ps += p;
                s4[nb][j] = p;
            }
            lj[j] += ps;
        }

#pragma unroll
        for (int nb = 0; nb < 4; ++nb) {
#pragma unroll
            for (int j = 0; j < 4; ++j) {
                int r = hi * 4 + j;
                uint32_t b = ((uint32_t)r * 128 + (nb * 16 + lo) * 2) ^ (((uint32_t)(r & 7)) << 4);
                *(u16*)((char*)&sP[w][0] + b) = f2bf(s4[nb][j]);
            }
        }

#pragma unroll
        for (int ck = 0; ck < 2; ++ck) {
            uint32_t bp = ((uint32_t)lo * 128 + ck * 64 + hi * 16) ^ (((uint32_t)(lo & 7)) << 4);
            bf16x8 pa = *reinterpret_cast<const bf16x8*>((const char*)&sP[w][0] + bp);
#pragma unroll
            for (int nb = 0; nb < 4; ++nb) {
                uint32_t bb = ((uint32_t)(nb * 16 + lo) * 128 + ck * 64 + hi * 16) ^ (((uint32_t)(lo & 7)) << 4);
                bf16x8 vf = *reinterpret_cast<const bf16x8*>((const char*)sVT + bb);
                o[nb] = __builtin_amdgcn_mfma_f32_16x16x32_bf16(pa, vf, o[nb], 0, 0, 0);
            }
        }
    }

#pragma unroll
    for (int j = 0; j < 4; ++j) {
        float s = lj[j];
        s += __shfl_xor(s, 1);
        s += __shfl_xor(s, 2);
        s += __shfl_xor(s, 4);
        s += __shfl_xor(s, 8);
        lj[j] = 1.0f / s;
    }
    const int bq = bh >> 4, h = bh & 15;
#pragma unroll
    for (int nb = 0; nb < 4; ++nb) {
#pragma unroll
        for (int j = 0; j < 4; ++j) {
            int q = q0 + w * 16 + hi * 4 + j;
            int d = nb * 16 + lo;
            O[((size_t)(bq * Ss + q)) * Dd + h * 64 + d] = f2bf(o[nb][j] * lj[j]);
        }
    }
}

// ---------- launch ----------
extern "C" void kernel_launch(void* const* d_in, const int* in_sizes, int n_in,
                              void* d_out, int out_size, void* d_ws, size_t ws_size,
                              hipStream_t stream) {
    const float* x  = (const float*)d_in[0];
    const float* Wq = (const float*)d_in[1];
    const float* Wk = (const float*)d_in[2];
    const float* Wv = (const float*)d_in[3];
    const float* Wo = (const float*)d_in[4];
    float* out = (float*)d_out;

    char* ws = (char*)d_ws;
    size_t off = 0;
    auto carve = [&](size_t bytes) -> char* {
        char* p = ws + off;
        off += (bytes + 255) & ~(size_t)255;
        return p;
    };
    float* cosT = (float*)carve((size_t)Ss * 64 * 4);
    float* sinT = (float*)carve((size_t)Ss * 64 * 4);
    u16* xb  = (u16*)carve((size_t)Mtot * Dd * 2);
    u16* wqb = (u16*)carve((size_t)Dd * Dd * 2);
    u16* wkb = (u16*)carve((size_t)Dd * Dd * 2);
    u16* wvb = (u16*)carve((size_t)Dd * Dd * 2);
    u16* wob = (u16*)carve((size_t)Dd * Dd * 2);
    u16* Qbb = (u16*)carve((size_t)Mtot * Dd * 2);
    u16* Kbb = (u16*)carve((size_t)Mtot * Dd * 2);
    u16* Vbb = (u16*)carve((size_t)Mtot * Dd * 2);
    u16* attb = (u16*)carve((size_t)Mtot * Dd * 2);

    prep<<<8704, 256, 0, stream>>>(x, Wq, Wk, Wv, Wo,
                                   xb, wqb, wkb, wvb, wob, cosT, sinT);

    gemm_k<0><<<dim3(Mtot / 128, Dd / 128, 3), 256, 0, stream>>>(
        xb, wqb, wkb, wvb, Qbb, Kbb, Vbb, cosT, sinT, Mtot, Dd, Dd);

    fattn<<<dim3(Ss / 64, Bb * Hh), 256, 0, stream>>>(Qbb, Kbb, Vbb, attb);

    gemm_k<1><<<dim3(Mtot / 128, Dd / 128, 1), 256, 0, stream>>>(
        attb, wob, wob, wob, out, out, out, nullptr, nullptr, Mtot, Dd, Dd);
}